// Round 2
// baseline (1570.368 us; speedup 1.0000x reference)
//
#include <hip/hip_runtime.h>
#include <hip/hip_bf16.h>

// Gated DeltaNet forward, MI355X. Inputs fp32, output fp32.
// Pipeline: cvt/transpose -> fused proj GEMM (bf16 MFMA, bf16 out) -> dwconv+silu
//           -> a/b GEMV -> DV-split sequential delta scan -> LN*gate -> output GEMM (fp32 out).
// ws usage ~236 MB (og aliases x_bf; early-return guard if ws_size too small).

#define HIDN 2048
#define NH   16
#define BB   2
#define TT   2048
#define MR   (BB*TT)      // 4096 rows
#define NPROJ 8192        // q|k|v|g concatenated
#define REC  400          // floats per (b,h,t) record: q128 k128 v128 a b pad
#define CHUNK 16          // scan steps staged per LDS buffer

typedef __attribute__((ext_vector_type(8))) short short8;
typedef __attribute__((ext_vector_type(4))) float f32x4;

__device__ __forceinline__ unsigned short f2bf(float f) {
  union { float f; unsigned u; } x; x.f = f;
  unsigned r = x.u + 0x7fffu + ((x.u >> 16) & 1u);
  return (unsigned short)(r >> 16);
}
__device__ __forceinline__ float bf2f(unsigned short u) {
  union { unsigned u; float f; } x; x.u = ((unsigned)u) << 16;
  return x.f;
}

__device__ __forceinline__ void gload16(const void* g, void* l) {
  __builtin_amdgcn_global_load_lds(
      (const __attribute__((address_space(1))) unsigned int*)g,
      (__attribute__((address_space(3))) unsigned int*)l, 16, 0, 0);
}

__device__ __forceinline__ float sigmoidf_(float v) { return 1.f / (1.f + __expf(-v)); }

// ---------------- fp32 -> bf16 elementwise (x) ----------------
__global__ __launch_bounds__(256) void cvt_f32_bf16(const float* __restrict__ in,
                                                    unsigned short* __restrict__ out) {
  int i = blockIdx.x * 256 + threadIdx.x;   // exactly MR*HIDN/4 threads
  float4 v = ((const float4*)in)[i];
  ushort4 u;
  u.x = f2bf(v.x); u.y = f2bf(v.y); u.z = f2bf(v.z); u.w = f2bf(v.w);
  ((ushort4*)out)[i] = u;
}

// ---------------- transpose + convert 2048x2048 weights ----------------
struct TPtrs { const float* src[5]; unsigned short* dst[5]; };

__global__ __launch_bounds__(256) void transpose_cvt(TPtrs p) {
  __shared__ float tile[32][33];
  const float* src = p.src[blockIdx.z];
  unsigned short* dst = p.dst[blockIdx.z];
  int c0 = blockIdx.x * 32, r0 = blockIdx.y * 32;
  int lx = threadIdx.x & 31, ly = threadIdx.x >> 5;  // 32 x 8
#pragma unroll
  for (int i = 0; i < 32; i += 8)
    tile[ly + i][lx] = src[(size_t)(r0 + ly + i) * 2048 + c0 + lx];
  __syncthreads();
#pragma unroll
  for (int i = 0; i < 32; i += 8)
    dst[(size_t)(c0 + ly + i) * 2048 + r0 + lx] = f2bf(tile[lx][ly + i]);
}

// ---------------- bf16 MFMA GEMM: C[M,N] = A[M,K] * BT[N,K]^T ----------------
// 128x128 tile, BK=64, 4 waves (2x2), global_load_lds staging (m97 structure).
template<int OUT_BF16>
__global__ __launch_bounds__(256) void gemm_bt(const unsigned short* __restrict__ A,
                                               const unsigned short* __restrict__ BT,
                                               void* __restrict__ C, int K, int ldc) {
  __shared__ unsigned short lA[128 * 64];
  __shared__ unsigned short lB[128 * 64];
  const int tid = threadIdx.x;
  const int wave = tid >> 6, lane = tid & 63;
  const int m0 = blockIdx.x * 128, n0 = blockIdx.y * 128;
  const int wm = wave >> 1, wn = wave & 1;
  const int lr = lane & 15, lk = (lane >> 4) * 8;
  const int srow = (lane >> 3), scol = (lane & 7) * 8;
  f32x4 acc[4][4] = {};
  for (int k0 = 0; k0 < K; k0 += 64) {
    __syncthreads();
#pragma unroll
    for (int c = 0; c < 4; ++c) {
      int seg = wave * 4 + c;
      int row = seg * 8 + srow;
      gload16(A + (size_t)(m0 + row) * K + k0 + scol, (void*)(lA + seg * 512));
      gload16(BT + (size_t)(n0 + row) * K + k0 + scol, (void*)(lB + seg * 512));
    }
    asm volatile("s_waitcnt vmcnt(0)" ::: "memory");
    __syncthreads();
#pragma unroll
    for (int kk = 0; kk < 2; ++kk) {
      short8 af[4], bg[4];
#pragma unroll
      for (int mi = 0; mi < 4; ++mi)
        af[mi] = *(const short8*)&lA[(wm * 64 + mi * 16 + lr) * 64 + kk * 32 + lk];
#pragma unroll
      for (int ni = 0; ni < 4; ++ni)
        bg[ni] = *(const short8*)&lB[(wn * 64 + ni * 16 + lr) * 64 + kk * 32 + lk];
#pragma unroll
      for (int mi = 0; mi < 4; ++mi)
#pragma unroll
        for (int ni = 0; ni < 4; ++ni)
          acc[mi][ni] = __builtin_amdgcn_mfma_f32_16x16x32_bf16(af[mi], bg[ni], acc[mi][ni], 0, 0, 0);
    }
  }
  const int orow = (lane >> 4) * 4, ocol = lane & 15;
#pragma unroll
  for (int mi = 0; mi < 4; ++mi)
#pragma unroll
    for (int ni = 0; ni < 4; ++ni) {
      int rbase = m0 + wm * 64 + mi * 16 + orow;
      int cc = n0 + wn * 64 + ni * 16 + ocol;
#pragma unroll
      for (int j = 0; j < 4; ++j) {
        if (OUT_BF16)
          ((unsigned short*)C)[(size_t)(rbase + j) * ldc + cc] = f2bf(acc[mi][ni][j]);
        else
          ((float*)C)[(size_t)(rbase + j) * ldc + cc] = acc[mi][ni][j];
      }
    }
}

// ---------------- alpha/beta GEMV: sigmoid(x@Wa+ba), sigmoid(x@Wb+bb) ----------------
__global__ __launch_bounds__(256) void gemv_ab(const float* __restrict__ x,
                                               const float* __restrict__ Wa, const float* __restrict__ ba,
                                               const float* __restrict__ Wb, const float* __restrict__ bb,
                                               float* __restrict__ qkvab) {
  __shared__ float red[2][4][16][16];  // [ab][row][grp][h]
  int tid = threadIdx.x;
  int h = tid & 15, grp = tid >> 4;
  int m0 = blockIdx.x * 4;
  float aa[4] = {0, 0, 0, 0}, bbv[4] = {0, 0, 0, 0};
  for (int kk = 0; kk < 128; ++kk) {
    int k = grp + kk * 16;
    float wa = Wa[k * 16 + h], wb = Wb[k * 16 + h];
#pragma unroll
    for (int r = 0; r < 4; ++r) {
      float xv = x[(size_t)(m0 + r) * HIDN + k];
      aa[r] += xv * wa; bbv[r] += xv * wb;
    }
  }
#pragma unroll
  for (int r = 0; r < 4; ++r) { red[0][r][grp][h] = aa[r]; red[1][r][grp][h] = bbv[r]; }
  __syncthreads();
  if (tid < 128) {
    int hh = tid & 15, ab = (tid >> 4) & 1, r = tid >> 5;
    float s = 0.f;
#pragma unroll
    for (int g = 0; g < 16; ++g) s += red[ab][r][g][hh];
    s += ab ? bb[hh] : ba[hh];
    s = sigmoidf_(s);
    int m = m0 + r; int b = m >> 11, t = m & 2047;
    qkvab[((size_t)(b * NH + hh) * TT + t) * REC + 384 + ab] = s;
  }
}

// ---------------- causal depthwise conv (KS=4) + SiLU, pack into qkvab ----------------
struct ConvPtrs { const float* w[3]; const float* bias[3]; };

__global__ __launch_bounds__(256) void conv_silu(const unsigned short* __restrict__ Y, ConvPtrs p,
                                                 float kscale, float* __restrict__ qkvab) {
  int proj = blockIdx.y;
  int idx = blockIdx.x * 256 + threadIdx.x;  // over B*T*2048
  int c = idx & 2047;
  int t = (idx >> 11) & 2047;
  int b = idx >> 22;
  const float* w = p.w[proj] + c * 4;
  float acc = p.bias[proj][c];
  const unsigned short* ycol = Y + (size_t)(b * TT) * NPROJ + proj * 2048 + c;
#pragma unroll
  for (int i = 0; i < 4; ++i) {
    int tt = t - 3 + i;
    if (tt >= 0) acc += w[i] * bf2f(ycol[(size_t)tt * NPROJ]);
  }
  float s = acc * sigmoidf_(acc);          // silu
  if (proj == 1) s *= kscale;              // fold DK^-0.5 into k
  int hh = c >> 7, d = c & 127;
  qkvab[((size_t)(b * NH + hh) * TT + t) * REC + proj * 128 + d] = s;
}

// ---------------- gated delta scan, DV split 8-way ----------------
// grid 256: bh = blk&31 (keeps the 8 DV-groups of one chain on one XCD), vg = blk>>5.
// 256 thr: r = tid>>4 (16 DV rows), s = tid&15 (16 k-segments of 8).
__global__ __launch_bounds__(256) void scan_kernel(const float* __restrict__ qkvab,
                                                   unsigned short* __restrict__ o) {
  __shared__ float buf[2][CHUNK * REC];  // 2 x 25.6 KB
  int bh = blockIdx.x & 31;
  int vg = blockIdx.x >> 5;
  int tid = threadIdx.x;
  int wave = tid >> 6, lane = tid & 63;
  int r = tid >> 4, s = tid & 15;
  const float* stream = qkvab + (size_t)bh * TT * REC;
  int b = bh >> 4, h = bh & 15;
  unsigned short* op = o + ((size_t)b * TT * NH + h) * 128 + vg * 16 + r;
  float S[8] = {0, 0, 0, 0, 0, 0, 0, 0};
  for (int c = wave; c < 25; c += 4)
    gload16(stream + c * 256 + lane * 4, (void*)(&buf[0][0] + c * 256));
  asm volatile("s_waitcnt vmcnt(0)" ::: "memory");
  __syncthreads();
  for (int ch = 0; ch < TT / CHUNK; ++ch) {
    int pb = ch & 1;
    if (ch + 1 < TT / CHUNK) {
      const float* src = stream + (size_t)(ch + 1) * CHUNK * REC;
      for (int c = wave; c < 25; c += 4)
        gload16(src + c * 256 + lane * 4, (void*)(&buf[pb ^ 1][0] + c * 256));
    }
    const float* rec = &buf[pb][0];
    for (int st = 0; st < CHUNK; ++st, rec += REC) {
      float4 k0 = *(const float4*)&rec[128 + s * 8];
      float4 k1 = *(const float4*)&rec[132 + s * 8];
      float4 q0 = *(const float4*)&rec[s * 8];
      float4 q1 = *(const float4*)&rec[4 + s * 8];
      float vt = rec[256 + vg * 16 + r];
      float al = rec[384], be = rec[385];
      // err partial over this thread's 8 k's, reduce over the 16 segment lanes
      float p = S[0] * k0.x + S[1] * k0.y + S[2] * k0.z + S[3] * k0.w
              + S[4] * k1.x + S[5] * k1.y + S[6] * k1.z + S[7] * k1.w;
      p += __shfl_xor(p, 1); p += __shfl_xor(p, 2);
      p += __shfl_xor(p, 4); p += __shfl_xor(p, 8);
      float err = p - vt;
      float c2 = be * err;
      S[0] = al * S[0] - c2 * k0.x;
      S[1] = al * S[1] - c2 * k0.y;
      S[2] = al * S[2] - c2 * k0.z;
      S[3] = al * S[3] - c2 * k0.w;
      S[4] = al * S[4] - c2 * k1.x;
      S[5] = al * S[5] - c2 * k1.y;
      S[6] = al * S[6] - c2 * k1.z;
      S[7] = al * S[7] - c2 * k1.w;
      float po = S[0] * q0.x + S[1] * q0.y + S[2] * q0.z + S[3] * q0.w
               + S[4] * q1.x + S[5] * q1.y + S[6] * q1.z + S[7] * q1.w;
      po += __shfl_xor(po, 1); po += __shfl_xor(po, 2);
      po += __shfl_xor(po, 4); po += __shfl_xor(po, 8);
      if (s == 0) op[(size_t)(ch * CHUNK + st) * (NH * 128)] = f2bf(po);
    }
    asm volatile("s_waitcnt vmcnt(0)" ::: "memory");
    __syncthreads();
  }
}

// ---------------- LayerNorm over DV, * sigmoid(gate), -> bf16 ----------------
__global__ __launch_bounds__(64) void ln_gate(const unsigned short* __restrict__ o,
                                              const unsigned short* __restrict__ Y,
                                              const float* __restrict__ lnw, const float* __restrict__ lnb,
                                              unsigned short* __restrict__ og) {
  int idx = blockIdx.x;          // (b*T+t)*16 + h
  int h = idx & 15; int bt = idx >> 4;
  int lane = threadIdx.x;
  const unsigned short* ob = o + (size_t)idx * 128;
  float o0 = bf2f(ob[lane]), o1 = bf2f(ob[lane + 64]);
  float s = o0 + o1, s2 = o0 * o0 + o1 * o1;
#pragma unroll
  for (int m = 1; m < 64; m <<= 1) { s += __shfl_xor(s, m); s2 += __shfl_xor(s2, m); }
  float mu = s * (1.f / 128.f);
  float var = s2 * (1.f / 128.f) - mu * mu;
  float rstd = rsqrtf(var + 1e-5f);
  const unsigned short* yg = Y + (size_t)bt * NPROJ + 6144 + h * 128;
  float g0 = sigmoidf_(bf2f(yg[lane])), g1 = sigmoidf_(bf2f(yg[lane + 64]));
  float r0 = ((o0 - mu) * rstd * lnw[lane] + lnb[lane]) * g0;
  float r1 = ((o1 - mu) * rstd * lnw[lane + 64] + lnb[lane + 64]) * g1;
  unsigned short* ogb = og + (size_t)bt * HIDN + h * 128;
  ogb[lane] = f2bf(r0); ogb[lane + 64] = f2bf(r1);
}

extern "C" void kernel_launch(void* const* d_in, const int* in_sizes, int n_in,
                              void* d_out, int out_size, void* d_ws, size_t ws_size,
                              hipStream_t stream) {
  (void)in_sizes; (void)n_in; (void)out_size;
  const float* x   = (const float*)d_in[0];
  const float* Wq  = (const float*)d_in[1];
  const float* Wk  = (const float*)d_in[2];
  const float* Wv  = (const float*)d_in[3];
  const float* Wa  = (const float*)d_in[4];
  const float* ba  = (const float*)d_in[5];
  const float* Wb  = (const float*)d_in[6];
  const float* bb  = (const float*)d_in[7];
  const float* Wg  = (const float*)d_in[8];
  const float* Wo  = (const float*)d_in[9];
  const float* cqw = (const float*)d_in[10];
  const float* cqb = (const float*)d_in[11];
  const float* ckw = (const float*)d_in[12];
  const float* ckb = (const float*)d_in[13];
  const float* cvw = (const float*)d_in[14];
  const float* cvb = (const float*)d_in[15];
  const float* lnw = (const float*)d_in[16];
  const float* lnb = (const float*)d_in[17];

  // ---- workspace layout (bytes) ----
  size_t need = 0;
  size_t o_WT    = need; need += (size_t)NPROJ * HIDN * 2;        // 32 MB  Wq|Wk|Wv|Wg ^T bf16
  size_t o_WoT   = need; need += (size_t)HIDN * HIDN * 2;         //  8 MB  Wo^T bf16
  size_t o_Y     = need; need += (size_t)MR * NPROJ * 2;          // 64 MB  proj out bf16
  size_t o_qkvab = need; need += (size_t)BB * NH * TT * REC * 4;  //100 MB  scan stream fp32
  size_t o_xog   = need; need += (size_t)MR * HIDN * 2;           // 16 MB  x_bf, later og
  size_t o_obf   = need; need += (size_t)MR * HIDN * 2;           // 16 MB  scan out bf16
  if (need > ws_size) return;  // diagnostic: leaves d_out zeroed -> absmax == max|ref| (2.47)

  char* ws = (char*)d_ws;
  unsigned short* WT_all = (unsigned short*)(ws + o_WT);
  unsigned short* WoT    = (unsigned short*)(ws + o_WoT);
  unsigned short* Y_all  = (unsigned short*)(ws + o_Y);
  float*          qkvab  = (float*)(ws + o_qkvab);
  unsigned short* x_bf   = (unsigned short*)(ws + o_xog);
  unsigned short* og     = (unsigned short*)(ws + o_xog);  // alias: x_bf dead after proj GEMM
  unsigned short* o_bf   = (unsigned short*)(ws + o_obf);

  cvt_f32_bf16<<<(MR * HIDN) / 4 / 256, 256, 0, stream>>>(x, x_bf);

  TPtrs tp;
  tp.src[0] = Wq; tp.src[1] = Wk; tp.src[2] = Wv; tp.src[3] = Wg; tp.src[4] = Wo;
  tp.dst[0] = WT_all;
  tp.dst[1] = WT_all + (size_t)2048 * 2048;
  tp.dst[2] = WT_all + (size_t)2 * 2048 * 2048;
  tp.dst[3] = WT_all + (size_t)3 * 2048 * 2048;
  tp.dst[4] = WoT;
  transpose_cvt<<<dim3(64, 64, 5), 256, 0, stream>>>(tp);

  gemv_ab<<<MR / 4, 256, 0, stream>>>(x, Wa, ba, Wb, bb, qkvab);

  // Y_all[4096, 8192] = x @ [Wq|Wk|Wv|Wg]   (bf16 out)
  gemm_bt<1><<<dim3(MR / 128, NPROJ / 128), 256, 0, stream>>>(x_bf, WT_all, (void*)Y_all, HIDN, NPROJ);

  ConvPtrs cp;
  cp.w[0] = cqw; cp.w[1] = ckw; cp.w[2] = cvw;
  cp.bias[0] = cqb; cp.bias[1] = ckb; cp.bias[2] = cvb;
  conv_silu<<<dim3((BB * TT * 2048) / 256, 3), 256, 0, stream>>>(Y_all, cp, 0.08838834764831845f, qkvab);

  scan_kernel<<<256, 256, 0, stream>>>(qkvab, o_bf);

  ln_gate<<<MR * NH, 64, 0, stream>>>(o_bf, Y_all, lnw, lnb, og);

  // out[4096, 2048] = og @ Wo   (fp32 out)
  gemm_bt<0><<<dim3(MR / 128, HIDN / 128), 256, 0, stream>>>(og, WoT, d_out, HIDN, HIDN);
}

// Round 3
// 1168.710 us; speedup vs baseline: 1.3437x; 1.3437x over previous
//
#include <hip/hip_runtime.h>
#include <hip/hip_bf16.h>

// Gated DeltaNet forward, MI355X. Inputs fp32, output fp32.
// Pipeline: cvt/transpose -> fused proj GEMM (bf16 MFMA, bf16 out) -> dwconv+silu
//           -> a/b GEMV -> DV-split sequential delta scan -> LN*gate -> output GEMM (fp32 out).
// R3: scan rewritten — full step-unroll (reg pipelining), 16B-stride team reads
//     (2-way min bank aliasing), register-buffered output stores off the barrier path.

#define HIDN 2048
#define NH   16
#define BB   2
#define TT   2048
#define MR   (BB*TT)      // 4096 rows
#define NPROJ 8192        // q|k|v|g concatenated
#define REC  400          // floats per (b,h,t) record: q128 k128 v128 a b pad
#define CHUNK 16          // scan steps staged per LDS buffer

typedef __attribute__((ext_vector_type(8))) short short8;
typedef __attribute__((ext_vector_type(4))) float f32x4;

__device__ __forceinline__ unsigned short f2bf(float f) {
  union { float f; unsigned u; } x; x.f = f;
  unsigned r = x.u + 0x7fffu + ((x.u >> 16) & 1u);
  return (unsigned short)(r >> 16);
}
__device__ __forceinline__ float bf2f(unsigned short u) {
  union { unsigned u; float f; } x; x.u = ((unsigned)u) << 16;
  return x.f;
}

__device__ __forceinline__ void gload16(const void* g, void* l) {
  __builtin_amdgcn_global_load_lds(
      (const __attribute__((address_space(1))) unsigned int*)g,
      (__attribute__((address_space(3))) unsigned int*)l, 16, 0, 0);
}

__device__ __forceinline__ float sigmoidf_(float v) { return 1.f / (1.f + __expf(-v)); }

// ---------------- fp32 -> bf16 elementwise (x) ----------------
__global__ __launch_bounds__(256) void cvt_f32_bf16(const float* __restrict__ in,
                                                    unsigned short* __restrict__ out) {
  int i = blockIdx.x * 256 + threadIdx.x;   // exactly MR*HIDN/4 threads
  float4 v = ((const float4*)in)[i];
  ushort4 u;
  u.x = f2bf(v.x); u.y = f2bf(v.y); u.z = f2bf(v.z); u.w = f2bf(v.w);
  ((ushort4*)out)[i] = u;
}

// ---------------- transpose + convert 2048x2048 weights ----------------
struct TPtrs { const float* src[5]; unsigned short* dst[5]; };

__global__ __launch_bounds__(256) void transpose_cvt(TPtrs p) {
  __shared__ float tile[32][33];
  const float* src = p.src[blockIdx.z];
  unsigned short* dst = p.dst[blockIdx.z];
  int c0 = blockIdx.x * 32, r0 = blockIdx.y * 32;
  int lx = threadIdx.x & 31, ly = threadIdx.x >> 5;  // 32 x 8
#pragma unroll
  for (int i = 0; i < 32; i += 8)
    tile[ly + i][lx] = src[(size_t)(r0 + ly + i) * 2048 + c0 + lx];
  __syncthreads();
#pragma unroll
  for (int i = 0; i < 32; i += 8)
    dst[(size_t)(c0 + ly + i) * 2048 + r0 + lx] = f2bf(tile[lx][ly + i]);
}

// ---------------- bf16 MFMA GEMM: C[M,N] = A[M,K] * BT[N,K]^T ----------------
// 128x128 tile, BK=64, 4 waves (2x2), global_load_lds staging (m97 structure).
template<int OUT_BF16>
__global__ __launch_bounds__(256) void gemm_bt(const unsigned short* __restrict__ A,
                                               const unsigned short* __restrict__ BT,
                                               void* __restrict__ C, int K, int ldc) {
  __shared__ unsigned short lA[128 * 64];
  __shared__ unsigned short lB[128 * 64];
  const int tid = threadIdx.x;
  const int wave = tid >> 6, lane = tid & 63;
  const int m0 = blockIdx.x * 128, n0 = blockIdx.y * 128;
  const int wm = wave >> 1, wn = wave & 1;
  const int lr = lane & 15, lk = (lane >> 4) * 8;
  const int srow = (lane >> 3), scol = (lane & 7) * 8;
  f32x4 acc[4][4] = {};
  for (int k0 = 0; k0 < K; k0 += 64) {
    __syncthreads();
#pragma unroll
    for (int c = 0; c < 4; ++c) {
      int seg = wave * 4 + c;
      int row = seg * 8 + srow;
      gload16(A + (size_t)(m0 + row) * K + k0 + scol, (void*)(lA + seg * 512));
      gload16(BT + (size_t)(n0 + row) * K + k0 + scol, (void*)(lB + seg * 512));
    }
    asm volatile("s_waitcnt vmcnt(0)" ::: "memory");
    __syncthreads();
#pragma unroll
    for (int kk = 0; kk < 2; ++kk) {
      short8 af[4], bg[4];
#pragma unroll
      for (int mi = 0; mi < 4; ++mi)
        af[mi] = *(const short8*)&lA[(wm * 64 + mi * 16 + lr) * 64 + kk * 32 + lk];
#pragma unroll
      for (int ni = 0; ni < 4; ++ni)
        bg[ni] = *(const short8*)&lB[(wn * 64 + ni * 16 + lr) * 64 + kk * 32 + lk];
#pragma unroll
      for (int mi = 0; mi < 4; ++mi)
#pragma unroll
        for (int ni = 0; ni < 4; ++ni)
          acc[mi][ni] = __builtin_amdgcn_mfma_f32_16x16x32_bf16(af[mi], bg[ni], acc[mi][ni], 0, 0, 0);
    }
  }
  const int orow = (lane >> 4) * 4, ocol = lane & 15;
#pragma unroll
  for (int mi = 0; mi < 4; ++mi)
#pragma unroll
    for (int ni = 0; ni < 4; ++ni) {
      int rbase = m0 + wm * 64 + mi * 16 + orow;
      int cc = n0 + wn * 64 + ni * 16 + ocol;
#pragma unroll
      for (int j = 0; j < 4; ++j) {
        if (OUT_BF16)
          ((unsigned short*)C)[(size_t)(rbase + j) * ldc + cc] = f2bf(acc[mi][ni][j]);
        else
          ((float*)C)[(size_t)(rbase + j) * ldc + cc] = acc[mi][ni][j];
      }
    }
}

// ---------------- alpha/beta GEMV: sigmoid(x@Wa+ba), sigmoid(x@Wb+bb) ----------------
__global__ __launch_bounds__(256) void gemv_ab(const float* __restrict__ x,
                                               const float* __restrict__ Wa, const float* __restrict__ ba,
                                               const float* __restrict__ Wb, const float* __restrict__ bb,
                                               float* __restrict__ qkvab) {
  __shared__ float red[2][4][16][16];  // [ab][row][grp][h]
  int tid = threadIdx.x;
  int h = tid & 15, grp = tid >> 4;
  int m0 = blockIdx.x * 4;
  float aa[4] = {0, 0, 0, 0}, bbv[4] = {0, 0, 0, 0};
  for (int kk = 0; kk < 128; ++kk) {
    int k = grp + kk * 16;
    float wa = Wa[k * 16 + h], wb = Wb[k * 16 + h];
#pragma unroll
    for (int r = 0; r < 4; ++r) {
      float xv = x[(size_t)(m0 + r) * HIDN + k];
      aa[r] += xv * wa; bbv[r] += xv * wb;
    }
  }
#pragma unroll
  for (int r = 0; r < 4; ++r) { red[0][r][grp][h] = aa[r]; red[1][r][grp][h] = bbv[r]; }
  __syncthreads();
  if (tid < 128) {
    int hh = tid & 15, ab = (tid >> 4) & 1, r = tid >> 5;
    float s = 0.f;
#pragma unroll
    for (int g = 0; g < 16; ++g) s += red[ab][r][g][hh];
    s += ab ? bb[hh] : ba[hh];
    s = sigmoidf_(s);
    int m = m0 + r; int b = m >> 11, t = m & 2047;
    qkvab[((size_t)(b * NH + hh) * TT + t) * REC + 384 + ab] = s;
  }
}

// ---------------- causal depthwise conv (KS=4) + SiLU, pack into qkvab ----------------
struct ConvPtrs { const float* w[3]; const float* bias[3]; };

__global__ __launch_bounds__(256) void conv_silu(const unsigned short* __restrict__ Y, ConvPtrs p,
                                                 float kscale, float* __restrict__ qkvab) {
  int proj = blockIdx.y;
  int idx = blockIdx.x * 256 + threadIdx.x;  // over B*T*2048
  int c = idx & 2047;
  int t = (idx >> 11) & 2047;
  int b = idx >> 22;
  const float* w = p.w[proj] + c * 4;
  float acc = p.bias[proj][c];
  const unsigned short* ycol = Y + (size_t)(b * TT) * NPROJ + proj * 2048 + c;
#pragma unroll
  for (int i = 0; i < 4; ++i) {
    int tt = t - 3 + i;
    if (tt >= 0) acc += w[i] * bf2f(ycol[(size_t)tt * NPROJ]);
  }
  float s = acc * sigmoidf_(acc);          // silu
  if (proj == 1) s *= kscale;              // fold DK^-0.5 into k
  int hh = c >> 7, d = c & 127;
  qkvab[((size_t)(b * NH + hh) * TT + t) * REC + proj * 128 + d] = s;
}

// ---------------- gated delta scan, DV split 8-way ----------------
// grid 256: bh = blk&31, vg = blk>>5. 256 thr: r = tid>>4 (16 DV rows),
// s = tid&15 (16-lane k-team). Lane s owns k/q floats [s*4,s*4+4) and
// [64+s*4, 64+s*4+4) -> 16B-stride ds_read_b128, 2-way bank aliasing (free).
// Step loop fully unrolled so LDS loads pipeline ahead of the shuffle chain.
__global__ __launch_bounds__(256, 1) void scan_kernel(const float* __restrict__ qkvab,
                                                      unsigned short* __restrict__ o) {
  __shared__ float buf[2][CHUNK * REC];  // 2 x 25.6 KB
  int bh = blockIdx.x & 31;
  int vg = blockIdx.x >> 5;
  int tid = threadIdx.x;
  int wave = tid >> 6, lane = tid & 63;
  int r = tid >> 4, s = tid & 15;
  const float* stream = qkvab + (size_t)bh * TT * REC;
  int b = bh >> 4, h = bh & 15;
  unsigned short* op = o + ((size_t)b * TT * NH + h) * 128 + vg * 16 + r;
  float S[8] = {0, 0, 0, 0, 0, 0, 0, 0};
  float pob[CHUNK];
  for (int c = wave; c < 25; c += 4)
    gload16(stream + c * 256 + lane * 4, (void*)(&buf[0][0] + c * 256));
  asm volatile("s_waitcnt vmcnt(0)" ::: "memory");
  __syncthreads();
  for (int ch = 0; ch < TT / CHUNK; ++ch) {
    int pb = ch & 1;
    if (ch + 1 < TT / CHUNK) {
      const float* src = stream + (size_t)(ch + 1) * CHUNK * REC;
      for (int c = wave; c < 25; c += 4)
        gload16(src + c * 256 + lane * 4, (void*)(&buf[pb ^ 1][0] + c * 256));
    }
    // store previous chunk's outputs (registers) — off the barrier-critical path
    if (ch > 0 && s == 0) {
      int tb = (ch - 1) * CHUNK;
#pragma unroll
      for (int j = 0; j < CHUNK; ++j)
        op[(size_t)(tb + j) * (NH * 128)] = f2bf(pob[j]);
    }
    const float* rec = &buf[pb][0];
#pragma unroll
    for (int st = 0; st < CHUNK; ++st) {
      const float* rr = rec + st * REC;
      float4 k0 = *(const float4*)&rr[128 + s * 4];
      float4 k1 = *(const float4*)&rr[192 + s * 4];
      float4 q0 = *(const float4*)&rr[s * 4];
      float4 q1 = *(const float4*)&rr[64 + s * 4];
      float vt = rr[256 + vg * 16 + r];
      float al = rr[384], be = rr[385];
      // err partial over this thread's 8 k's, reduce over the 16 team lanes
      float p = S[0] * k0.x + S[1] * k0.y + S[2] * k0.z + S[3] * k0.w
              + S[4] * k1.x + S[5] * k1.y + S[6] * k1.z + S[7] * k1.w;
      p += __shfl_xor(p, 1); p += __shfl_xor(p, 2);
      p += __shfl_xor(p, 4); p += __shfl_xor(p, 8);
      float c2 = be * (p - vt);
      S[0] = al * S[0] - c2 * k0.x;
      S[1] = al * S[1] - c2 * k0.y;
      S[2] = al * S[2] - c2 * k0.z;
      S[3] = al * S[3] - c2 * k0.w;
      S[4] = al * S[4] - c2 * k1.x;
      S[5] = al * S[5] - c2 * k1.y;
      S[6] = al * S[6] - c2 * k1.z;
      S[7] = al * S[7] - c2 * k1.w;
      float po = S[0] * q0.x + S[1] * q0.y + S[2] * q0.z + S[3] * q0.w
               + S[4] * q1.x + S[5] * q1.y + S[6] * q1.z + S[7] * q1.w;
      po += __shfl_xor(po, 1); po += __shfl_xor(po, 2);
      po += __shfl_xor(po, 4); po += __shfl_xor(po, 8);
      pob[st] = po;
    }
    asm volatile("s_waitcnt vmcnt(0)" ::: "memory");
    __syncthreads();
  }
  if (s == 0) {
    int tb = (TT / CHUNK - 1) * CHUNK;
#pragma unroll
    for (int j = 0; j < CHUNK; ++j)
      op[(size_t)(tb + j) * (NH * 128)] = f2bf(pob[j]);
  }
}

// ---------------- LayerNorm over DV, * sigmoid(gate), -> bf16 ----------------
__global__ __launch_bounds__(64) void ln_gate(const unsigned short* __restrict__ o,
                                              const unsigned short* __restrict__ Y,
                                              const float* __restrict__ lnw, const float* __restrict__ lnb,
                                              unsigned short* __restrict__ og) {
  int idx = blockIdx.x;          // (b*T+t)*16 + h
  int h = idx & 15; int bt = idx >> 4;
  int lane = threadIdx.x;
  const unsigned short* ob = o + (size_t)idx * 128;
  float o0 = bf2f(ob[lane]), o1 = bf2f(ob[lane + 64]);
  float s = o0 + o1, s2 = o0 * o0 + o1 * o1;
#pragma unroll
  for (int m = 1; m < 64; m <<= 1) { s += __shfl_xor(s, m); s2 += __shfl_xor(s2, m); }
  float mu = s * (1.f / 128.f);
  float var = s2 * (1.f / 128.f) - mu * mu;
  float rstd = rsqrtf(var + 1e-5f);
  const unsigned short* yg = Y + (size_t)bt * NPROJ + 6144 + h * 128;
  float g0 = sigmoidf_(bf2f(yg[lane])), g1 = sigmoidf_(bf2f(yg[lane + 64]));
  float r0 = ((o0 - mu) * rstd * lnw[lane] + lnb[lane]) * g0;
  float r1 = ((o1 - mu) * rstd * lnw[lane + 64] + lnb[lane + 64]) * g1;
  unsigned short* ogb = og + (size_t)bt * HIDN + h * 128;
  ogb[lane] = f2bf(r0); ogb[lane + 64] = f2bf(r1);
}

extern "C" void kernel_launch(void* const* d_in, const int* in_sizes, int n_in,
                              void* d_out, int out_size, void* d_ws, size_t ws_size,
                              hipStream_t stream) {
  (void)in_sizes; (void)n_in; (void)out_size;
  const float* x   = (const float*)d_in[0];
  const float* Wq  = (const float*)d_in[1];
  const float* Wk  = (const float*)d_in[2];
  const float* Wv  = (const float*)d_in[3];
  const float* Wa  = (const float*)d_in[4];
  const float* ba  = (const float*)d_in[5];
  const float* Wb  = (const float*)d_in[6];
  const float* bb  = (const float*)d_in[7];
  const float* Wg  = (const float*)d_in[8];
  const float* Wo  = (const float*)d_in[9];
  const float* cqw = (const float*)d_in[10];
  const float* cqb = (const float*)d_in[11];
  const float* ckw = (const float*)d_in[12];
  const float* ckb = (const float*)d_in[13];
  const float* cvw = (const float*)d_in[14];
  const float* cvb = (const float*)d_in[15];
  const float* lnw = (const float*)d_in[16];
  const float* lnb = (const float*)d_in[17];

  // ---- workspace layout (bytes) ----
  size_t need = 0;
  size_t o_WT    = need; need += (size_t)NPROJ * HIDN * 2;        // 32 MB  Wq|Wk|Wv|Wg ^T bf16
  size_t o_WoT   = need; need += (size_t)HIDN * HIDN * 2;         //  8 MB  Wo^T bf16
  size_t o_Y     = need; need += (size_t)MR * NPROJ * 2;          // 64 MB  proj out bf16
  size_t o_qkvab = need; need += (size_t)BB * NH * TT * REC * 4;  //100 MB  scan stream fp32
  size_t o_xog   = need; need += (size_t)MR * HIDN * 2;           // 16 MB  x_bf, later og
  size_t o_obf   = need; need += (size_t)MR * HIDN * 2;           // 16 MB  scan out bf16
  if (need > ws_size) return;  // diagnostic: leaves d_out zeroed -> absmax == max|ref| (2.47)

  char* ws = (char*)d_ws;
  unsigned short* WT_all = (unsigned short*)(ws + o_WT);
  unsigned short* WoT    = (unsigned short*)(ws + o_WoT);
  unsigned short* Y_all  = (unsigned short*)(ws + o_Y);
  float*          qkvab  = (float*)(ws + o_qkvab);
  unsigned short* x_bf   = (unsigned short*)(ws + o_xog);
  unsigned short* og     = (unsigned short*)(ws + o_xog);  // alias: x_bf dead after proj GEMM
  unsigned short* o_bf   = (unsigned short*)(ws + o_obf);

  cvt_f32_bf16<<<(MR * HIDN) / 4 / 256, 256, 0, stream>>>(x, x_bf);

  TPtrs tp;
  tp.src[0] = Wq; tp.src[1] = Wk; tp.src[2] = Wv; tp.src[3] = Wg; tp.src[4] = Wo;
  tp.dst[0] = WT_all;
  tp.dst[1] = WT_all + (size_t)2048 * 2048;
  tp.dst[2] = WT_all + (size_t)2 * 2048 * 2048;
  tp.dst[3] = WT_all + (size_t)3 * 2048 * 2048;
  tp.dst[4] = WoT;
  transpose_cvt<<<dim3(64, 64, 5), 256, 0, stream>>>(tp);

  gemv_ab<<<MR / 4, 256, 0, stream>>>(x, Wa, ba, Wb, bb, qkvab);

  // Y_all[4096, 8192] = x @ [Wq|Wk|Wv|Wg]   (bf16 out)
  gemm_bt<1><<<dim3(MR / 128, NPROJ / 128), 256, 0, stream>>>(x_bf, WT_all, (void*)Y_all, HIDN, NPROJ);

  ConvPtrs cp;
  cp.w[0] = cqw; cp.w[1] = ckw; cp.w[2] = cvw;
  cp.bias[0] = cqb; cp.bias[1] = ckb; cp.bias[2] = cvb;
  conv_silu<<<dim3((BB * TT * 2048) / 256, 3), 256, 0, stream>>>(Y_all, cp, 0.08838834764831845f, qkvab);

  scan_kernel<<<256, 256, 0, stream>>>(qkvab, o_bf);

  ln_gate<<<MR * NH, 64, 0, stream>>>(o_bf, Y_all, lnw, lnb, og);

  // out[4096, 2048] = og @ Wo   (fp32 out)
  gemm_bt<0><<<dim3(MR / 128, HIDN / 128), 256, 0, stream>>>(og, WoT, d_out, HIDN, HIDN);
}

// Round 5
// 1009.852 us; speedup vs baseline: 1.5550x; 1.1573x over previous
//
#include <hip/hip_runtime.h>
#include <hip/hip_bf16.h>

// Gated DeltaNet forward, MI355X. Inputs fp32, output fp32.
// Pipeline: cvt/transpose -> fused proj GEMM (bf16 MFMA, bf16 out) -> dwconv+silu
//           -> a/b GEMV -> DV-split sequential delta scan -> LN*gate -> output GEMM (fp32 out).
// R4 (resubmit; R4 bench was an acquisition timeout): scan reductions via DPP
//     row_ror add (VALU pipe) instead of __shfl_xor (ds_bpermute, LDS pipe)
//     + hand-treed dot products. ~60cy recurrence path.

#define HIDN 2048
#define NH   16
#define BB   2
#define TT   2048
#define MR   (BB*TT)      // 4096 rows
#define NPROJ 8192        // q|k|v|g concatenated
#define REC  400          // floats per (b,h,t) record: q128 k128 v128 a b pad
#define CHUNK 16          // scan steps staged per LDS buffer

typedef __attribute__((ext_vector_type(8))) short short8;
typedef __attribute__((ext_vector_type(4))) float f32x4;

__device__ __forceinline__ unsigned short f2bf(float f) {
  union { float f; unsigned u; } x; x.f = f;
  unsigned r = x.u + 0x7fffu + ((x.u >> 16) & 1u);
  return (unsigned short)(r >> 16);
}
__device__ __forceinline__ float bf2f(unsigned short u) {
  union { unsigned u; float f; } x; x.u = ((unsigned)u) << 16;
  return x.f;
}

__device__ __forceinline__ void gload16(const void* g, void* l) {
  __builtin_amdgcn_global_load_lds(
      (const __attribute__((address_space(1))) unsigned int*)g,
      (__attribute__((address_space(3))) unsigned int*)l, 16, 0, 0);
}

__device__ __forceinline__ float sigmoidf_(float v) { return 1.f / (1.f + __expf(-v)); }

// ---- 16-lane row reduction via DPP rotate-add (VALU pipe, no LDS crossbar) ----
template<int CTRL>
__device__ __forceinline__ float dppadd(float x) {
  union { float f; int i; } a, b;
  a.f = x;
  b.i = __builtin_amdgcn_update_dpp(0, a.i, CTRL, 0xf, 0xf, true);
  return a.f + b.f;
}
__device__ __forceinline__ float red16(float x) {
  x = dppadd<0x128>(x);  // row_ror:8
  x = dppadd<0x124>(x);  // row_ror:4
  x = dppadd<0x122>(x);  // row_ror:2
  x = dppadd<0x121>(x);  // row_ror:1
  return x;
}

// ---------------- fp32 -> bf16 elementwise (x) ----------------
__global__ __launch_bounds__(256) void cvt_f32_bf16(const float* __restrict__ in,
                                                    unsigned short* __restrict__ out) {
  int i = blockIdx.x * 256 + threadIdx.x;   // exactly MR*HIDN/4 threads
  float4 v = ((const float4*)in)[i];
  ushort4 u;
  u.x = f2bf(v.x); u.y = f2bf(v.y); u.z = f2bf(v.z); u.w = f2bf(v.w);
  ((ushort4*)out)[i] = u;
}

// ---------------- transpose + convert 2048x2048 weights ----------------
struct TPtrs { const float* src[5]; unsigned short* dst[5]; };

__global__ __launch_bounds__(256) void transpose_cvt(TPtrs p) {
  __shared__ float tile[32][33];
  const float* src = p.src[blockIdx.z];
  unsigned short* dst = p.dst[blockIdx.z];
  int c0 = blockIdx.x * 32, r0 = blockIdx.y * 32;
  int lx = threadIdx.x & 31, ly = threadIdx.x >> 5;  // 32 x 8
#pragma unroll
  for (int i = 0; i < 32; i += 8)
    tile[ly + i][lx] = src[(size_t)(r0 + ly + i) * 2048 + c0 + lx];
  __syncthreads();
#pragma unroll
  for (int i = 0; i < 32; i += 8)
    dst[(size_t)(c0 + ly + i) * 2048 + r0 + lx] = f2bf(tile[lx][ly + i]);
}

// ---------------- bf16 MFMA GEMM: C[M,N] = A[M,K] * BT[N,K]^T ----------------
// 128x128 tile, BK=64, 4 waves (2x2), global_load_lds staging (m97 structure).
template<int OUT_BF16>
__global__ __launch_bounds__(256) void gemm_bt(const unsigned short* __restrict__ A,
                                               const unsigned short* __restrict__ BT,
                                               void* __restrict__ C, int K, int ldc) {
  __shared__ unsigned short lA[128 * 64];
  __shared__ unsigned short lB[128 * 64];
  const int tid = threadIdx.x;
  const int wave = tid >> 6, lane = tid & 63;
  const int m0 = blockIdx.x * 128, n0 = blockIdx.y * 128;
  const int wm = wave >> 1, wn = wave & 1;
  const int lr = lane & 15, lk = (lane >> 4) * 8;
  const int srow = (lane >> 3), scol = (lane & 7) * 8;
  f32x4 acc[4][4] = {};
  for (int k0 = 0; k0 < K; k0 += 64) {
    __syncthreads();
#pragma unroll
    for (int c = 0; c < 4; ++c) {
      int seg = wave * 4 + c;
      int row = seg * 8 + srow;
      gload16(A + (size_t)(m0 + row) * K + k0 + scol, (void*)(lA + seg * 512));
      gload16(BT + (size_t)(n0 + row) * K + k0 + scol, (void*)(lB + seg * 512));
    }
    asm volatile("s_waitcnt vmcnt(0)" ::: "memory");
    __syncthreads();
#pragma unroll
    for (int kk = 0; kk < 2; ++kk) {
      short8 af[4], bg[4];
#pragma unroll
      for (int mi = 0; mi < 4; ++mi)
        af[mi] = *(const short8*)&lA[(wm * 64 + mi * 16 + lr) * 64 + kk * 32 + lk];
#pragma unroll
      for (int ni = 0; ni < 4; ++ni)
        bg[ni] = *(const short8*)&lB[(wn * 64 + ni * 16 + lr) * 64 + kk * 32 + lk];
#pragma unroll
      for (int mi = 0; mi < 4; ++mi)
#pragma unroll
        for (int ni = 0; ni < 4; ++ni)
          acc[mi][ni] = __builtin_amdgcn_mfma_f32_16x16x32_bf16(af[mi], bg[ni], acc[mi][ni], 0, 0, 0);
    }
  }
  const int orow = (lane >> 4) * 4, ocol = lane & 15;
#pragma unroll
  for (int mi = 0; mi < 4; ++mi)
#pragma unroll
    for (int ni = 0; ni < 4; ++ni) {
      int rbase = m0 + wm * 64 + mi * 16 + orow;
      int cc = n0 + wn * 64 + ni * 16 + ocol;
#pragma unroll
      for (int j = 0; j < 4; ++j) {
        if (OUT_BF16)
          ((unsigned short*)C)[(size_t)(rbase + j) * ldc + cc] = f2bf(acc[mi][ni][j]);
        else
          ((float*)C)[(size_t)(rbase + j) * ldc + cc] = acc[mi][ni][j];
      }
    }
}

// ---------------- alpha/beta GEMV: sigmoid(x@Wa+ba), sigmoid(x@Wb+bb) ----------------
__global__ __launch_bounds__(256) void gemv_ab(const float* __restrict__ x,
                                               const float* __restrict__ Wa, const float* __restrict__ ba,
                                               const float* __restrict__ Wb, const float* __restrict__ bb,
                                               float* __restrict__ qkvab) {
  __shared__ float red[2][4][16][16];  // [ab][row][grp][h]
  int tid = threadIdx.x;
  int h = tid & 15, grp = tid >> 4;
  int m0 = blockIdx.x * 4;
  float aa[4] = {0, 0, 0, 0}, bbv[4] = {0, 0, 0, 0};
  for (int kk = 0; kk < 128; ++kk) {
    int k = grp + kk * 16;
    float wa = Wa[k * 16 + h], wb = Wb[k * 16 + h];
#pragma unroll
    for (int r = 0; r < 4; ++r) {
      float xv = x[(size_t)(m0 + r) * HIDN + k];
      aa[r] += xv * wa; bbv[r] += xv * wb;
    }
  }
#pragma unroll
  for (int r = 0; r < 4; ++r) { red[0][r][grp][h] = aa[r]; red[1][r][grp][h] = bbv[r]; }
  __syncthreads();
  if (tid < 128) {
    int hh = tid & 15, ab = (tid >> 4) & 1, r = tid >> 5;
    float s = 0.f;
#pragma unroll
    for (int g = 0; g < 16; ++g) s += red[ab][r][g][hh];
    s += ab ? bb[hh] : ba[hh];
    s = sigmoidf_(s);
    int m = m0 + r; int b = m >> 11, t = m & 2047;
    qkvab[((size_t)(b * NH + hh) * TT + t) * REC + 384 + ab] = s;
  }
}

// ---------------- causal depthwise conv (KS=4) + SiLU, pack into qkvab ----------------
struct ConvPtrs { const float* w[3]; const float* bias[3]; };

__global__ __launch_bounds__(256) void conv_silu(const unsigned short* __restrict__ Y, ConvPtrs p,
                                                 float kscale, float* __restrict__ qkvab) {
  int proj = blockIdx.y;
  int idx = blockIdx.x * 256 + threadIdx.x;  // over B*T*2048
  int c = idx & 2047;
  int t = (idx >> 11) & 2047;
  int b = idx >> 22;
  const float* w = p.w[proj] + c * 4;
  float acc = p.bias[proj][c];
  const unsigned short* ycol = Y + (size_t)(b * TT) * NPROJ + proj * 2048 + c;
#pragma unroll
  for (int i = 0; i < 4; ++i) {
    int tt = t - 3 + i;
    if (tt >= 0) acc += w[i] * bf2f(ycol[(size_t)tt * NPROJ]);
  }
  float s = acc * sigmoidf_(acc);          // silu
  if (proj == 1) s *= kscale;              // fold DK^-0.5 into k
  int hh = c >> 7, d = c & 127;
  qkvab[((size_t)(b * NH + hh) * TT + t) * REC + proj * 128 + d] = s;
}

// ---------------- gated delta scan, DV split 8-way ----------------
// grid 256: bh = blk&31, vg = blk>>5. 256 thr: r = tid>>4 (16 DV rows),
// s = tid&15 (16-lane k-team, 16B-stride reads = free 2-way bank aliasing).
// Reductions: DPP row_ror add (VALU). Dots hand-treed. Steps fully unrolled.
__global__ __launch_bounds__(256, 1) void scan_kernel(const float* __restrict__ qkvab,
                                                      unsigned short* __restrict__ o) {
  __shared__ float buf[2][CHUNK * REC];  // 2 x 25.6 KB
  int bh = blockIdx.x & 31;
  int vg = blockIdx.x >> 5;
  int tid = threadIdx.x;
  int wave = tid >> 6, lane = tid & 63;
  int r = tid >> 4, s = tid & 15;
  const float* stream = qkvab + (size_t)bh * TT * REC;
  int b = bh >> 4, h = bh & 15;
  unsigned short* op = o + ((size_t)b * TT * NH + h) * 128 + vg * 16 + r;
  float S[8] = {0, 0, 0, 0, 0, 0, 0, 0};
  float pob[CHUNK];
  for (int c = wave; c < 25; c += 4)
    gload16(stream + c * 256 + lane * 4, (void*)(&buf[0][0] + c * 256));
  asm volatile("s_waitcnt vmcnt(0)" ::: "memory");
  __syncthreads();
  for (int ch = 0; ch < TT / CHUNK; ++ch) {
    int pb = ch & 1;
    if (ch + 1 < TT / CHUNK) {
      const float* src = stream + (size_t)(ch + 1) * CHUNK * REC;
      for (int c = wave; c < 25; c += 4)
        gload16(src + c * 256 + lane * 4, (void*)(&buf[pb ^ 1][0] + c * 256));
    }
    // store previous chunk's outputs (registers) — off the barrier-critical path
    if (ch > 0 && s == 0) {
      int tb = (ch - 1) * CHUNK;
#pragma unroll
      for (int j = 0; j < CHUNK; ++j)
        op[(size_t)(tb + j) * (NH * 128)] = f2bf(pob[j]);
    }
    const float* rec = &buf[pb][0];
#pragma unroll
    for (int st = 0; st < CHUNK; ++st) {
      const float* rr = rec + st * REC;
      float4 k0 = *(const float4*)&rr[128 + s * 4];
      float4 k1 = *(const float4*)&rr[192 + s * 4];
      float4 q0 = *(const float4*)&rr[s * 4];
      float4 q1 = *(const float4*)&rr[64 + s * 4];
      float vt = rr[256 + vg * 16 + r];
      float al = rr[384], be = rr[385];
      // S·k : tree (4cy-dep levels), then 16-lane DPP reduce (VALU pipe)
      float a0 = S[0] * k0.x, a1 = S[1] * k0.y, a2 = S[2] * k0.z, a3 = S[3] * k0.w;
      float a4 = S[4] * k1.x, a5 = S[5] * k1.y, a6 = S[6] * k1.z, a7 = S[7] * k1.w;
      float p = ((a0 + a1) + (a2 + a3)) + ((a4 + a5) + (a6 + a7));
      p = red16(p);
      float c2 = be * (p - vt);
      S[0] = al * S[0] - c2 * k0.x;
      S[1] = al * S[1] - c2 * k0.y;
      S[2] = al * S[2] - c2 * k0.z;
      S[3] = al * S[3] - c2 * k0.w;
      S[4] = al * S[4] - c2 * k1.x;
      S[5] = al * S[5] - c2 * k1.y;
      S[6] = al * S[6] - c2 * k1.z;
      S[7] = al * S[7] - c2 * k1.w;
      float b0 = S[0] * q0.x, b1 = S[1] * q0.y, b2 = S[2] * q0.z, b3 = S[3] * q0.w;
      float b4 = S[4] * q1.x, b5 = S[5] * q1.y, b6 = S[6] * q1.z, b7 = S[7] * q1.w;
      float po = ((b0 + b1) + (b2 + b3)) + ((b4 + b5) + (b6 + b7));
      po = red16(po);
      pob[st] = po;
    }
    asm volatile("s_waitcnt vmcnt(0)" ::: "memory");
    __syncthreads();
  }
  if (s == 0) {
    int tb = (TT / CHUNK - 1) * CHUNK;
#pragma unroll
    for (int j = 0; j < CHUNK; ++j)
      op[(size_t)(tb + j) * (NH * 128)] = f2bf(pob[j]);
  }
}

// ---------------- LayerNorm over DV, * sigmoid(gate), -> bf16 ----------------
__global__ __launch_bounds__(64) void ln_gate(const unsigned short* __restrict__ o,
                                              const unsigned short* __restrict__ Y,
                                              const float* __restrict__ lnw, const float* __restrict__ lnb,
                                              unsigned short* __restrict__ og) {
  int idx = blockIdx.x;          // (b*T+t)*16 + h
  int h = idx & 15; int bt = idx >> 4;
  int lane = threadIdx.x;
  const unsigned short* ob = o + (size_t)idx * 128;
  float o0 = bf2f(ob[lane]), o1 = bf2f(ob[lane + 64]);
  float s = o0 + o1, s2 = o0 * o0 + o1 * o1;
#pragma unroll
  for (int m = 1; m < 64; m <<= 1) { s += __shfl_xor(s, m); s2 += __shfl_xor(s2, m); }
  float mu = s * (1.f / 128.f);
  float var = s2 * (1.f / 128.f) - mu * mu;
  float rstd = rsqrtf(var + 1e-5f);
  const unsigned short* yg = Y + (size_t)bt * NPROJ + 6144 + h * 128;
  float g0 = sigmoidf_(bf2f(yg[lane])), g1 = sigmoidf_(bf2f(yg[lane + 64]));
  float r0 = ((o0 - mu) * rstd * lnw[lane] + lnb[lane]) * g0;
  float r1 = ((o1 - mu) * rstd * lnw[lane + 64] + lnb[lane + 64]) * g1;
  unsigned short* ogb = og + (size_t)bt * HIDN + h * 128;
  ogb[lane] = f2bf(r0); ogb[lane + 64] = f2bf(r1);
}

extern "C" void kernel_launch(void* const* d_in, const int* in_sizes, int n_in,
                              void* d_out, int out_size, void* d_ws, size_t ws_size,
                              hipStream_t stream) {
  (void)in_sizes; (void)n_in; (void)out_size;
  const float* x   = (const float*)d_in[0];
  const float* Wq  = (const float*)d_in[1];
  const float* Wk  = (const float*)d_in[2];
  const float* Wv  = (const float*)d_in[3];
  const float* Wa  = (const float*)d_in[4];
  const float* ba  = (const float*)d_in[5];
  const float* Wb  = (const float*)d_in[6];
  const float* bb  = (const float*)d_in[7];
  const float* Wg  = (const float*)d_in[8];
  const float* Wo  = (const float*)d_in[9];
  const float* cqw = (const float*)d_in[10];
  const float* cqb = (const float*)d_in[11];
  const float* ckw = (const float*)d_in[12];
  const float* ckb = (const float*)d_in[13];
  const float* cvw = (const float*)d_in[14];
  const float* cvb = (const float*)d_in[15];
  const float* lnw = (const float*)d_in[16];
  const float* lnb = (const float*)d_in[17];

  // ---- workspace layout (bytes) ----
  size_t need = 0;
  size_t o_WT    = need; need += (size_t)NPROJ * HIDN * 2;        // 32 MB  Wq|Wk|Wv|Wg ^T bf16
  size_t o_WoT   = need; need += (size_t)HIDN * HIDN * 2;         //  8 MB  Wo^T bf16
  size_t o_Y     = need; need += (size_t)MR * NPROJ * 2;          // 64 MB  proj out bf16
  size_t o_qkvab = need; need += (size_t)BB * NH * TT * REC * 4;  //100 MB  scan stream fp32
  size_t o_xog   = need; need += (size_t)MR * HIDN * 2;           // 16 MB  x_bf, later og
  size_t o_obf   = need; need += (size_t)MR * HIDN * 2;           // 16 MB  scan out bf16
  if (need > ws_size) return;  // diagnostic: leaves d_out zeroed -> absmax == max|ref| (2.47)

  char* ws = (char*)d_ws;
  unsigned short* WT_all = (unsigned short*)(ws + o_WT);
  unsigned short* WoT    = (unsigned short*)(ws + o_WoT);
  unsigned short* Y_all  = (unsigned short*)(ws + o_Y);
  float*          qkvab  = (float*)(ws + o_qkvab);
  unsigned short* x_bf   = (unsigned short*)(ws + o_xog);
  unsigned short* og     = (unsigned short*)(ws + o_xog);  // alias: x_bf dead after proj GEMM
  unsigned short* o_bf   = (unsigned short*)(ws + o_obf);

  cvt_f32_bf16<<<(MR * HIDN) / 4 / 256, 256, 0, stream>>>(x, x_bf);

  TPtrs tp;
  tp.src[0] = Wq; tp.src[1] = Wk; tp.src[2] = Wv; tp.src[3] = Wg; tp.src[4] = Wo;
  tp.dst[0] = WT_all;
  tp.dst[1] = WT_all + (size_t)2048 * 2048;
  tp.dst[2] = WT_all + (size_t)2 * 2048 * 2048;
  tp.dst[3] = WT_all + (size_t)3 * 2048 * 2048;
  tp.dst[4] = WoT;
  transpose_cvt<<<dim3(64, 64, 5), 256, 0, stream>>>(tp);

  gemv_ab<<<MR / 4, 256, 0, stream>>>(x, Wa, ba, Wb, bb, qkvab);

  // Y_all[4096, 8192] = x @ [Wq|Wk|Wv|Wg]   (bf16 out)
  gemm_bt<1><<<dim3(MR / 128, NPROJ / 128), 256, 0, stream>>>(x_bf, WT_all, (void*)Y_all, HIDN, NPROJ);

  ConvPtrs cp;
  cp.w[0] = cqw; cp.w[1] = ckw; cp.w[2] = cvw;
  cp.bias[0] = cqb; cp.bias[1] = ckb; cp.bias[2] = cvb;
  conv_silu<<<dim3((BB * TT * 2048) / 256, 3), 256, 0, stream>>>(Y_all, cp, 0.08838834764831845f, qkvab);

  scan_kernel<<<256, 256, 0, stream>>>(qkvab, o_bf);

  ln_gate<<<MR * NH, 64, 0, stream>>>(o_bf, Y_all, lnw, lnb, og);

  // out[4096, 2048] = og @ Wo   (fp32 out)
  gemm_bt<0><<<dim3(MR / 128, HIDN / 128), 256, 0, stream>>>(og, WoT, d_out, HIDN, HIDN);
}